// Round 7
// baseline (258.028 us; speedup 1.0000x reference)
//
#include <hip/hip_runtime.h>
#include <math.h>

#define NC   1000      // classes
#define DD   4096      // dense dim
#define BB   8192      // batch

#define MAIN_BLOCKS (NC * 2)           // 2 chunks of 2048 d's per class
#define CE_BLOCKS   (BB / 4)           // 4 waves/block, 1 sample/wave
#define TOT_BLOCKS  (MAIN_BLOCKS + CE_BLOCKS)   // 4048
#define MAXN 144                       // max samples per class (~Poisson(8.2)) + pad room
#define NSLOT 32                       // loss accumulator slots (contention spread)
#define LN2  0.69314718055994531f

// ws: 0: loss1 double[32] | 256: loss2 double[32]   (memset 512 B)

// per-element accumulate (y hoisted: bce = sum[max(x,0) + ln2*log2(1+e)] - y.sum(x))
#define ACCX(xv, aAcc, sAcc)                                                  \
    {                                                                         \
        float e   = __expf(-fabsf(xv));                                       \
        float p1  = 1.f + e;                                                  \
        float inv = __builtin_amdgcn_rcpf(p1);                                \
        aAcc += (xv >= 0.f) ? inv : e * inv;                                  \
        sAcc += xv;                                                           \
        bceA += fmaxf(xv, 0.f);                                               \
        bceB += __log2f(p1);                                                  \
    }

// DMA one 2-row batch (rows sidx[bb], sidx[bb+1], this block's 2048-col chunk)
// into LDS buffer bs. 4 x global_load_lds(16B): each wave's lanes cover
// bytes [lane*16] of each 4KB quarter -- EXACTLY the bytes that wave later
// ds_reads (thread t consumes floats t*4 of each quarter). So stage->consume
// needs only a per-wave vmcnt, NO __syncthreads.
#define STAGE2(bb, bs)                                                        \
    {                                                                         \
        int rA_ = sidx[(bb)];                                                 \
        int rB_ = sidx[(bb) + 1];                                             \
        const float* g0_ = gbase + ((size_t)rA_ << 12) + tof;                 \
        const float* g2_ = gbase + ((size_t)rB_ << 12) + tof;                 \
        float* l_ = xbuf + (bs) * 4096 + tof;                                 \
        __builtin_amdgcn_global_load_lds(                                     \
            (const __attribute__((address_space(1))) unsigned int*)(g0_),     \
            (__attribute__((address_space(3))) unsigned int*)(l_), 16, 0, 0); \
        __builtin_amdgcn_global_load_lds(                                     \
            (const __attribute__((address_space(1))) unsigned int*)(g0_ + 1024),\
            (__attribute__((address_space(3))) unsigned int*)(l_ + 1024), 16, 0, 0);\
        __builtin_amdgcn_global_load_lds(                                     \
            (const __attribute__((address_space(1))) unsigned int*)(g2_),     \
            (__attribute__((address_space(3))) unsigned int*)(l_ + 2048), 16, 0, 0);\
        __builtin_amdgcn_global_load_lds(                                     \
            (const __attribute__((address_space(1))) unsigned int*)(g2_ + 1024),\
            (__attribute__((address_space(3))) unsigned int*)(l_ + 3072), 16, 0, 0);\
    }

// LATENCY MODEL (R0-R6): register gather caps in-flight at ~64B/wave ->
// ~0.8 KB/CU vs the ~9 KB/CU needed for 6.3 TB/s => stuck at 1.2 TB/s.
// global_load_lds stages with ZERO VGPR cost per outstanding load:
// 4 KB in flight per wave, double-buffered, counted vmcnt (never drain
// mid-loop). VGPR stays ~44 (no xa arrays).
__global__ __launch_bounds__(256, 4) void fused_k(const float* __restrict__ logits,
                                                  const float* __restrict__ dense_out,
                                                  const int*   __restrict__ target,
                                                  const float* __restrict__ dense_labels,
                                                  float* __restrict__ out,
                                                  double* __restrict__ loss1,
                                                  double* __restrict__ loss2) {
    int bx = blockIdx.x;
    int t  = threadIdx.x;
    int wave = t >> 6;
    int lane = t & 63;

    __shared__ float xbuf[8192];   // 2 bufs x (2 rows x 2048 floats) = 32 KB
    __shared__ int   sidx[MAXN];
    __shared__ int   s_n;
    __shared__ float red[4];

    // interleave: even bx < 4000 are main blocks, everything else CE
    bool is_main = ((bx & 1) == 0) && (bx < 2 * MAIN_BLOCKS);

    if (is_main) {
        // ------------- main path: one (class, 2048-d chunk) per block ------
        int mb    = bx >> 1;            // 0..1999
        int c     = mb >> 1;
        int chunk = mb & 1;
        int dbase = chunk * 2048 + (t << 2);

        if (t == 0) s_n = 0;
        __syncthreads();

        const float* gbase = dense_out + chunk * 2048;
        int tof = t << 2;               // this thread's float offset in each quarter

        // scan all targets (32 KB, L1/L2-resident) and compact class-c samples
        const int4* tp = (const int4*)target;
        #pragma unroll
        for (int k = 0; k < 8; ++k) {
            int4 v = tp[k * 256 + t];
            int s0 = (k * 256 + t) * 4;
            if (v.x == c) { int p = atomicAdd(&s_n, 1); sidx[p] = s0;     }
            if (v.y == c) { int p = atomicAdd(&s_n, 1); sidx[p] = s0 + 1; }
            if (v.z == c) { int p = atomicAdd(&s_n, 1); sidx[p] = s0 + 2; }
            if (v.w == c) { int p = atomicAdd(&s_n, 1); sidx[p] = s0 + 3; }
        }
        __syncthreads();
        int n  = s_n;
        int n2 = (n + 1) & ~1;
        // pad to even with a duplicate so the tail batch's 2nd-row staging is
        // a valid (harmless) load; its ACCX is skipped wave-uniformly below.
        if (t == 0 && n2 != n) sidx[n] = sidx[0];
        __syncthreads();

        float a0 = 0.f, a1 = 0.f, a2 = 0.f, a3 = 0.f;
        float a4 = 0.f, a5 = 0.f, a6 = 0.f, a7 = 0.f;
        float s0 = 0.f, s1 = 0.f, s2 = 0.f, s3 = 0.f;
        float s4 = 0.f, s5 = 0.f, s6 = 0.f, s7 = 0.f;
        float bceA = 0.f, bceB = 0.f;

        if (n2 > 0) {
            STAGE2(0, 0);               // prologue: batch 0 -> buf 0
            int bsel = 0;
            for (int base = 0; base < n2; base += 2) {
                bool more = (base + 2) < n2;
                if (more) {
                    STAGE2(base + 2, bsel ^ 1);     // prefetch next batch
                    // wait for CURRENT batch only; next batch's 4 DMAs stay
                    // in flight across the compute (counted vmcnt, never 0
                    // mid-loop). "memory" clobber stops ds_read hoisting.
                    asm volatile("s_waitcnt vmcnt(4)" ::: "memory");
                } else {
                    asm volatile("s_waitcnt vmcnt(0)" ::: "memory");
                }
                const float4* b4 = (const float4*)(xbuf + bsel * 4096);
                float4 x0 = b4[t];          // row0, cols [tof, tof+4)
                float4 x1 = b4[256 + t];    // row0, cols [1024+tof, ...)
                float4 x2 = b4[512 + t];    // row1 lower
                float4 x3 = b4[768 + t];    // row1 upper

                ACCX(x0.x, a0, s0) ACCX(x0.y, a1, s1)
                ACCX(x0.z, a2, s2) ACCX(x0.w, a3, s3)
                ACCX(x1.x, a4, s4) ACCX(x1.y, a5, s5)
                ACCX(x1.z, a6, s6) ACCX(x1.w, a7, s7)
                if (base + 1 < n) {     // false only for the padded tail row
                    ACCX(x2.x, a0, s0) ACCX(x2.y, a1, s1)
                    ACCX(x2.z, a2, s2) ACCX(x2.w, a3, s3)
                    ACCX(x3.x, a4, s4) ACCX(x3.y, a5, s5)
                    ACCX(x3.z, a6, s6) ACCX(x3.w, a7, s7)
                }
                bsel ^= 1;
            }
        }

        // epilogue: y enters here only (y-hoist)
        const float4* yp = (const float4*)(dense_labels + (size_t)c * DD + dbase);
        float4 y0 = yp[0];
        float4 y1 = yp[256];
        float bce = bceA + LN2 * bceB
                  - (y0.x * s0 + y0.y * s1 + y0.z * s2 + y0.w * s3
                   + y1.x * s4 + y1.y * s5 + y1.z * s6 + y1.w * s7);

        // out+1 is the [NC,DD] segment-sum (4B-aligned only -> dword stores)
        float* p = out + 1 + (size_t)c * DD + dbase;
        p[0] = a0; p[1] = a1; p[2] = a2; p[3] = a3;
        p[1024] = a4; p[1025] = a5; p[1026] = a6; p[1027] = a7;

        if (chunk == 0 && t == 0) out[1 + (size_t)NC * DD + c] = (float)n;

        #pragma unroll
        for (int o2 = 32; o2 > 0; o2 >>= 1) bce += __shfl_xor(bce, o2);
        if (lane == 0) red[wave] = bce;
        __syncthreads();
        if (t == 0)
            atomicAdd(&loss2[mb & (NSLOT - 1)],
                      (double)(red[0] + red[1] + red[2] + red[3]));
    } else {
        // ------------- CE path: 4 waves/block, one sample per wave ---------
        int ce_i = (bx < 2 * MAIN_BLOCKS) ? (bx >> 1) : (bx - MAIN_BLOCKS);
        int i = ce_i * 4 + wave;
        const float* row = logits + (size_t)i * NC;
        int j0 = lane * 4;

        float4 r0 = *(const float4*)(row + j0);
        float4 r1 = *(const float4*)(row + j0 + 256);
        float4 r2 = *(const float4*)(row + j0 + 512);
        float4 r3;
        if (j0 + 768 < NC) r3 = *(const float4*)(row + j0 + 768);
        else r3 = make_float4(-INFINITY, -INFINITY, -INFINITY, -INFINITY);
        float tl = row[target[i]];

        float mx = fmaxf(fmaxf(fmaxf(r0.x, r0.y), fmaxf(r0.z, r0.w)),
                         fmaxf(fmaxf(r1.x, r1.y), fmaxf(r1.z, r1.w)));
        mx = fmaxf(mx, fmaxf(fmaxf(r2.x, r2.y), fmaxf(r2.z, r2.w)));
        mx = fmaxf(mx, fmaxf(fmaxf(r3.x, r3.y), fmaxf(r3.z, r3.w)));
        #pragma unroll
        for (int o = 32; o > 0; o >>= 1) mx = fmaxf(mx, __shfl_xor(mx, o));

        float s = __expf(r0.x - mx) + __expf(r0.y - mx) + __expf(r0.z - mx) + __expf(r0.w - mx)
                + __expf(r1.x - mx) + __expf(r1.y - mx) + __expf(r1.z - mx) + __expf(r1.w - mx)
                + __expf(r2.x - mx) + __expf(r2.y - mx) + __expf(r2.z - mx) + __expf(r2.w - mx)
                + __expf(r3.x - mx) + __expf(r3.y - mx) + __expf(r3.z - mx) + __expf(r3.w - mx);
        #pragma unroll
        for (int o = 32; o > 0; o >>= 1) s += __shfl_xor(s, o);

        if (lane == 0) red[wave] = -(tl - mx - __logf(s));
        __syncthreads();
        if (t == 0)
            atomicAdd(&loss1[ce_i & (NSLOT - 1)],
                      (double)(red[0] + red[1] + red[2] + red[3]));
    }
}

__global__ void fin_k(const double* __restrict__ loss1,
                      const double* __restrict__ loss2,
                      float* __restrict__ out) {
    double l1 = 0.0, l2 = 0.0;
    #pragma unroll
    for (int i = 0; i < NSLOT; ++i) { l1 += loss1[i]; l2 += loss2[i]; }
    out[0] = (float)(0.5 * (l1 / (double)BB) +
                     0.5 * (l2 / ((double)BB * (double)DD)));
}

extern "C" void kernel_launch(void* const* d_in, const int* in_sizes, int n_in,
                              void* d_out, int out_size, void* d_ws, size_t ws_size,
                              hipStream_t stream) {
    const float* logits       = (const float*)d_in[0];
    const float* dense_out    = (const float*)d_in[1];
    const int*   target       = (const int*)d_in[2];
    const float* dense_labels = (const float*)d_in[3];
    float* out = (float*)d_out;

    char* ws = (char*)d_ws;
    double* loss1 = (double*)(ws + 0);
    double* loss2 = (double*)(ws + 256);

    hipMemsetAsync(d_ws, 0, 512, stream);

    fused_k<<<TOT_BLOCKS, 256, 0, stream>>>(logits, dense_out, target,
                                            dense_labels, out, loss1, loss2);
    fin_k<<<1, 1, 0, stream>>>(loss1, loss2, out);
}